// Round 19
// baseline (378.009 us; speedup 1.0000x reference)
//
#include <hip/hip_runtime.h>
#include <hip/hip_bf16.h>
#include <math.h>

// ---------------------------------------------------------------------------
// TransformerBlock on MI355X (gfx950).
// QKV: gemm8<128,256> EPI5 -- V columns written TRANSPOSED directly to vt
//      (vtr kernel eliminated). O: gemm8 EPI3 (bf16 x2).
// FFN1: gemm97 EPI2 (gelu). FFN2: gemm97 EPI4 (fp32 out, bf16 resid).
// Attn: fixed-max softmax w/ MFMA-computed l (R17). Supertile XCD mapping.
// ---------------------------------------------------------------------------

typedef __attribute__((ext_vector_type(8))) short bf16x8;
typedef __attribute__((ext_vector_type(4))) float f32x4;

#define AS1 __attribute__((address_space(1)))
#define AS3 __attribute__((address_space(3)))

__device__ __forceinline__ void gl_lds16(const void* g, void* l) {
  __builtin_amdgcn_global_load_lds((const AS1 void*)g, (AS3 void*)l, 16, 0, 0);
}

// Exact gelu-tanh via exp identity: tanh(|y|) = (1-e^{-2|y|})/(1+e^{-2|y|}).
__device__ __forceinline__ float gelu_f(float x) {
  const float c = 0.7978845608028654f;  // sqrt(2/pi)
  const float y = c * (x + 0.044715f * x * x * x);
  const float ay = fabsf(y);
  const float e = __expf(-2.0f * ay);
  float t = (1.0f - e) / (1.0f + e);
  t = copysignf(t, y);
  return 0.5f * x * (1.0f + t);
}

__device__ __forceinline__ float bf2f(short s) {
  unsigned u = ((unsigned)(unsigned short)s) << 16;
  return __builtin_bit_cast(float, u);
}
__device__ __forceinline__ short f2bf(float f) {
  __hip_bfloat16 h = __float2bfloat16(f);
  return __builtin_bit_cast(short, h);
}

// ---------------------------------------------------------------------------
// All weight transposes in ONE launch: W [K,N] fp32 -> WT [N,K] bf16
// ---------------------------------------------------------------------------
__global__ void __launch_bounds__(256) tcvt_all(
    const float* __restrict__ Wq, const float* __restrict__ Wk,
    const float* __restrict__ Wv, const float* __restrict__ Wo,
    const float* __restrict__ W1, const float* __restrict__ W2,
    __hip_bfloat16* __restrict__ WqkvT, __hip_bfloat16* __restrict__ WoT,
    __hip_bfloat16* __restrict__ W1T, __hip_bfloat16* __restrict__ W2T) {
  __shared__ float t[32][33];
  const int bid = blockIdx.x;
  const float* W;
  __hip_bfloat16* WT;
  int K, N, n0, k0;
  if (bid < 4096) {
    const int which = bid >> 10, r = bid & 1023;
    K = 1024; N = 1024;
    n0 = (r & 31) * 32; k0 = (r >> 5) * 32;
    W = which == 0 ? Wq : which == 1 ? Wk : which == 2 ? Wv : Wo;
    WT = which < 3 ? WqkvT + which * 1024 * 1024 : WoT;
  } else if (bid < 8192) {
    const int r = bid - 4096;
    K = 1024; N = 4096;
    n0 = (r & 127) * 32; k0 = (r >> 7) * 32;
    W = W1; WT = W1T;
  } else {
    const int r = bid - 8192;
    K = 4096; N = 1024;
    n0 = (r & 31) * 32; k0 = (r >> 5) * 32;
    W = W2; WT = W2T;
  }
  const int tx = threadIdx.x, ty0 = threadIdx.y;  // 32 x 8
#pragma unroll
  for (int i = 0; i < 4; i++) {
    int ty = ty0 + i * 8;
    t[ty][tx] = W[(size_t)(k0 + ty) * N + n0 + tx];
  }
  __syncthreads();
#pragma unroll
  for (int i = 0; i < 4; i++) {
    int ty = ty0 + i * 8;
    WT[(size_t)(n0 + ty) * K + k0 + tx] = __float2bfloat16(t[tx][ty]);
  }
}

// ---------------------------------------------------------------------------
// LayerNorm over D=1024 (fp32 in -> bf16 out)
// ---------------------------------------------------------------------------
__global__ void __launch_bounds__(256) ln_kernel(
    const float* __restrict__ x, const float* __restrict__ gma,
    const float* __restrict__ bta, __hip_bfloat16* __restrict__ out) {
  const int row = blockIdx.x;
  const int tid = threadIdx.x;
  const float4 v = ((const float4*)(x + (size_t)row * 1024))[tid];
  float s = v.x + v.y + v.z + v.w;
  float s2 = v.x * v.x + v.y * v.y + v.z * v.z + v.w * v.w;
#pragma unroll
  for (int m = 32; m; m >>= 1) {
    s += __shfl_xor(s, m);
    s2 += __shfl_xor(s2, m);
  }
  __shared__ float red[8];
  const int w = tid >> 6, lane = tid & 63;
  if (lane == 0) { red[w] = s; red[4 + w] = s2; }
  __syncthreads();
  s = red[0] + red[1] + red[2] + red[3];
  s2 = red[4] + red[5] + red[6] + red[7];
  const float mu = s * (1.0f / 1024.0f);
  const float var = s2 * (1.0f / 1024.0f) - mu * mu;
  const float rs = rsqrtf(var + 1e-5f);
  const float4 gv = ((const float4*)gma)[tid];
  const float4 bv = ((const float4*)bta)[tid];
  __hip_bfloat16* orow = out + (size_t)row * 1024 + tid * 4;
  orow[0] = __float2bfloat16((v.x - mu) * rs * gv.x + bv.x);
  orow[1] = __float2bfloat16((v.y - mu) * rs * gv.y + bv.y);
  orow[2] = __float2bfloat16((v.z - mu) * rs * gv.z + bv.z);
  orow[3] = __float2bfloat16((v.w - mu) * rs * gv.w + bv.w);
}

// ---------------------------------------------------------------------------
// LayerNorm over D=1024 (bf16 in -> bf16 out)
// ---------------------------------------------------------------------------
__global__ void __launch_bounds__(256) ln_bf16_kernel(
    const __hip_bfloat16* __restrict__ x, const float* __restrict__ gma,
    const float* __restrict__ bta, __hip_bfloat16* __restrict__ out) {
  const int row = blockIdx.x;
  const int tid = threadIdx.x;
  const short4 raw = ((const short4*)(x + (size_t)row * 1024))[tid];
  const float v0 = bf2f(raw.x), v1 = bf2f(raw.y), v2 = bf2f(raw.z),
              v3 = bf2f(raw.w);
  float s = v0 + v1 + v2 + v3;
  float s2 = v0 * v0 + v1 * v1 + v2 * v2 + v3 * v3;
#pragma unroll
  for (int m = 32; m; m >>= 1) {
    s += __shfl_xor(s, m);
    s2 += __shfl_xor(s2, m);
  }
  __shared__ float red[8];
  const int w = tid >> 6, lane = tid & 63;
  if (lane == 0) { red[w] = s; red[4 + w] = s2; }
  __syncthreads();
  s = red[0] + red[1] + red[2] + red[3];
  s2 = red[4] + red[5] + red[6] + red[7];
  const float mu = s * (1.0f / 1024.0f);
  const float var = s2 * (1.0f / 1024.0f) - mu * mu;
  const float rs = rsqrtf(var + 1e-5f);
  const float4 gv = ((const float4*)gma)[tid];
  const float4 bv = ((const float4*)bta)[tid];
  __hip_bfloat16* orow = out + (size_t)row * 1024 + tid * 4;
  orow[0] = __float2bfloat16((v0 - mu) * rs * gv.x + bv.x);
  orow[1] = __float2bfloat16((v1 - mu) * rs * gv.y + bv.y);
  orow[2] = __float2bfloat16((v2 - mu) * rs * gv.z + bv.z);
  orow[3] = __float2bfloat16((v3 - mu) * rs * gv.w + bv.w);
}

// ---------------------------------------------------------------------------
// GEMM, 8-phase, SINGLE barrier per phase. C = A*B^T, bf16 in, fp32 acc.
// EPI 0: bf16 | 3: bf16 = .+bias+resid(fp32) | 5: QKV fused V-transpose
// (bn<8 -> normal bf16 to outp; bn>=8 -> short4 transposed stores to vtp).
// ---------------------------------------------------------------------------
template <int BM, int BN, int EPI>
__global__ void __launch_bounds__(512, 2) gemm8(
    const __hip_bfloat16* __restrict__ Ap, const __hip_bfloat16* __restrict__ Bp,
    void* __restrict__ outp, const float* __restrict__ bias,
    const float* __restrict__ resid, int N, int K,
    __hip_bfloat16* __restrict__ vtp) {
  constexpr int PM = BM / 2;
  constexpr int MR = PM / 16;
  constexpr int NPH = MR / 2;
  constexpr int HA = BM / 128;
  constexpr int ABYTES = BM * 128;
  constexpr int BUFB = ABYTES + BN * 128;
  __shared__ __attribute__((aligned(128))) char smem[2 * BUFB];

  const int tid = threadIdx.x;
  const int lane = tid & 63, w = tid >> 6;
  const int wr = w >> 2, wc = w & 3;
  const int cr = lane & 15, g = lane >> 4;

  const int gx = gridDim.x;
  const int nwg = gx * gridDim.y;
  const int orig = blockIdx.y * gx + blockIdx.x;
  const int f = (orig & 7) * (nwg >> 3) + (orig >> 3);
  const int sid = f >> 4, wit = f & 15;
  const int stm = gx >> 2;
  const int bm = (sid % stm) * 4 + (wit & 3);
  const int bn = (sid / stm) * 4 + (wit >> 2);
  const int bmr = bm * BM, bnr = bn * BN;
  const int nkt = K >> 6;

  const int srow8 = lane >> 3;
  const int ssl = ((lane & 7) ^ srow8) * 8;
  unsigned aofs[2][2], bofs[2][2];
#pragma unroll
  for (int h = 0; h < 2; h++)
#pragma unroll
    for (int c = 0; c < 2; c++) {
      const int ha = (h < HA) ? h : 0;
      aofs[h][c] =
          (unsigned)(((bmr + ha * 128 + (w + c * 8) * 8 + srow8) * K + ssl) * 2);
      bofs[h][c] =
          (unsigned)(((bnr + h * 128 + (w + c * 8) * 8 + srow8) * K + ssl) * 2);
    }

  const int rk = cr & 7;
  const char* aP[2][2];
  const char* bP[2][2];
#pragma unroll
  for (int bf = 0; bf < 2; bf++)
#pragma unroll
    for (int ks = 0; ks < 2; ks++) {
      aP[bf][ks] =
          smem + bf * BUFB + (wr * PM + cr) * 128 + ((ks * 4 + g) ^ rk) * 16;
      bP[bf][ks] = smem + bf * BUFB + ABYTES + (wc * 64 + cr) * 128 +
                   ((ks * 4 + g) ^ rk) * 16;
    }

#define STG_A(BUF, tt, h)                                                     \
  do {                                                                        \
    const unsigned col = (unsigned)(tt) * 128u;                               \
    gl_lds16((const char*)Ap + aofs[h][0] + col,                              \
             smem + (BUF) * BUFB + (h) * 16384 + w * 1024);                   \
    gl_lds16((const char*)Ap + aofs[h][1] + col,                              \
             smem + (BUF) * BUFB + (h) * 16384 + (w + 8) * 1024);             \
  } while (0)
#define STG_B(BUF, tt, h)                                                     \
  do {                                                                        \
    const unsigned col = (unsigned)(tt) * 128u;                               \
    gl_lds16((const char*)Bp + bofs[h][0] + col,                              \
             smem + (BUF) * BUFB + ABYTES + (h) * 16384 + w * 1024);          \
    gl_lds16((const char*)Bp + bofs[h][1] + col,                              \
             smem + (BUF) * BUFB + ABYTES + (h) * 16384 + (w + 8) * 1024);    \
  } while (0)

  f32x4 acc[MR][4];
#pragma unroll
  for (int i = 0; i < MR; i++)
#pragma unroll
    for (int j = 0; j < 4; j++) acc[i][j] = (f32x4){0.f, 0.f, 0.f, 0.f};
  bf16x8 bv[4][2];

#pragma unroll
  for (int h = 0; h < HA; h++) STG_A(0, 0, h);
  STG_B(0, 0, 0); STG_B(0, 0, 1);
  STG_B(1, 1, 0); STG_B(1, 1, 1);

#define TILE_BODY(BUF, t)                                                     \
  {                                                                           \
    asm volatile("s_waitcnt vmcnt(4)" ::: "memory");                          \
    __builtin_amdgcn_s_barrier();                                             \
    const int tA = ((t) + 1 < nkt) ? (t) + 1 : (t) - 1;                       \
    const int tB = ((t) + 2 < nkt) ? (t) + 2 : (t);                           \
    _Pragma("unroll") for (int q = 0; q < NPH; q++) {                         \
      bf16x8 av[2][2];                                                        \
      _Pragma("unroll") for (int mm = 0; mm < 2; mm++)                        \
          _Pragma("unroll") for (int ks = 0; ks < 2; ks++) av[mm][ks] =       \
          *(const bf16x8*)(aP[BUF][ks] + (q * 2 + mm) * 2048);                \
      if (q == 0) {                                                           \
        _Pragma("unroll") for (int n = 0; n < 4; n++)                         \
            _Pragma("unroll") for (int ks = 0; ks < 2; ks++) bv[n][ks] =      \
            *(const bf16x8*)(bP[BUF][ks] + n * 2048);                         \
      }                                                                       \
      if constexpr (NPH == 4) {                                               \
        if (q == 0) { STG_A((BUF) ^ 1, tA, 0); }                              \
        else if (q == 1) { STG_A((BUF) ^ 1, tA, 1); }                         \
        else if (q == 2) { STG_B(BUF, tB, 0); }                               \
        else { STG_B(BUF, tB, 1); }                                           \
      } else {                                                                \
        if (q == 0) { STG_A((BUF) ^ 1, tA, 0); }                              \
        else { STG_B(BUF, tB, 0); STG_B(BUF, tB, 1); }                        \
      }                                                                       \
      __builtin_amdgcn_s_barrier();                                           \
      asm volatile("s_waitcnt lgkmcnt(0)" ::: "memory");                      \
      __builtin_amdgcn_s_setprio(1);                                          \
      _Pragma("unroll") for (int mm = 0; mm < 2; mm++)                        \
          _Pragma("unroll") for (int n = 0; n < 4; n++)                       \
              _Pragma("unroll") for (int ks = 0; ks < 2; ks++)                \
                  acc[q * 2 + mm][n] =                                        \
          __builtin_amdgcn_mfma_f32_16x16x32_bf16(av[mm][ks], bv[n][ks],      \
                                                  acc[q * 2 + mm][n], 0, 0, 0); \
      __builtin_amdgcn_s_setprio(0);                                          \
    }                                                                         \
  }

  for (int t = 0; t < nkt; t += 2) {
    TILE_BODY(0, t)
    TILE_BODY(1, t + 1)
  }
  asm volatile("s_waitcnt vmcnt(0)" ::: "memory");

  if (EPI == 5 && bnr >= 2048) {
    // V columns: write transposed to vtp[(b*1024 + hdg)*2048 + s].
    // rr = 4 consecutive rows = 4 consecutive s -> one short4 store.
    const int bq = bmr >> 11;               // batch (block-uniform)
    const int sbase = (bmr & 2047) + wr * PM + g * 4;
#pragma unroll
    for (int m = 0; m < MR; m++) {
      const int s0 = sbase + m * 16;
#pragma unroll
      for (int n = 0; n < 4; n++) {
        const int hdg = bnr - 2048 + wc * 64 + n * 16 + cr;
        short4 pk;
        pk.x = f2bf(acc[m][n][0]);
        pk.y = f2bf(acc[m][n][1]);
        pk.z = f2bf(acc[m][n][2]);
        pk.w = f2bf(acc[m][n][3]);
        *(short4*)&vtp[((size_t)bq * 1024 + hdg) * 2048 + s0] = pk;
      }
    }
    return;
  }

#pragma unroll
  for (int m = 0; m < MR; m++) {
#pragma unroll
    for (int rr = 0; rr < 4; rr++) {
      const int row = bmr + wr * PM + m * 16 + g * 4 + rr;
#pragma unroll
      for (int n = 0; n < 4; n++) {
        const int col = bnr + wc * 64 + n * 16 + cr;
        float v = acc[m][n][rr];
        if (EPI == 0 || EPI == 5) {
          ((__hip_bfloat16*)outp)[(size_t)row * N + col] = __float2bfloat16(v);
        } else {  // EPI == 3: bf16 out, fp32 resid
          v += bias[col] + resid[(size_t)row * N + col];
          ((__hip_bfloat16*)outp)[(size_t)row * N + col] = __float2bfloat16(v);
        }
      }
    }
  }
#undef STG_A
#undef STG_B
#undef TILE_BODY
}

// ---------------------------------------------------------------------------
// GEMM, m97 structure: 128x128, 256 thr, single-buffer, supertile map.
// EPI 2: bf16 = gelu(.+bias) | EPI 4: fp32 out = .+bias+resid(bf16)
// ---------------------------------------------------------------------------
template <int EPI>
__global__ void __launch_bounds__(256) gemm97(
    const __hip_bfloat16* __restrict__ Ap, const __hip_bfloat16* __restrict__ Bp,
    void* __restrict__ outp, const float* __restrict__ bias,
    const void* __restrict__ resid, int N, int K) {
  __shared__ __hip_bfloat16 sA[128 * 64];
  __shared__ __hip_bfloat16 sB[128 * 64];
  const int tid = threadIdx.x;
  const int lane = tid & 63, w = tid >> 6;
  const int wr = w >> 1, wc = w & 1;
  const int cr = lane & 15, g = lane >> 4;

  const int gx = gridDim.x;
  const int nwg = gx * gridDim.y;
  const int orig = blockIdx.y * gx + blockIdx.x;
  const int f = (orig & 7) * (nwg >> 3) + (orig >> 3);
  const int sid = f >> 4, wit = f & 15;
  const int stm = gx >> 2;
  const int bm = (sid % stm) * 4 + (wit & 3);
  const int bn = (sid / stm) * 4 + (wit >> 2);
  const int bmr = bm * 128, bnr = bn * 128;

  const int l8 = lane >> 3;
  const int ssl = ((lane & 7) ^ l8) * 8;
  const int rk = cr & 7;

  f32x4 acc[4][4];
#pragma unroll
  for (int i = 0; i < 4; i++)
#pragma unroll
    for (int j = 0; j < 4; j++) acc[i][j] = (f32x4){0.f, 0.f, 0.f, 0.f};

  for (int k0 = 0; k0 < K; k0 += 64) {
#pragma unroll
    for (int i = 0; i < 4; i++) {
      const int chunk = w * 4 + i;
      const int row = chunk * 8 + l8;
      gl_lds16(Ap + (size_t)(bmr + row) * K + k0 + ssl, sA + chunk * 512);
      gl_lds16(Bp + (size_t)(bnr + row) * K + k0 + ssl, sB + chunk * 512);
    }
    __syncthreads();
#pragma unroll
    for (int ks = 0; ks < 2; ks++) {
      bf16x8 a[4], b[4];
#pragma unroll
      for (int m = 0; m < 4; m++)
        a[m] = *(const bf16x8*)(sA + (wr * 64 + m * 16 + cr) * 64 +
                                ((ks * 4 + g) ^ rk) * 8);
#pragma unroll
      for (int n = 0; n < 4; n++)
        b[n] = *(const bf16x8*)(sB + (wc * 64 + n * 16 + cr) * 64 +
                                ((ks * 4 + g) ^ rk) * 8);
#pragma unroll
      for (int m = 0; m < 4; m++)
#pragma unroll
        for (int n = 0; n < 4; n++)
          acc[m][n] =
              __builtin_amdgcn_mfma_f32_16x16x32_bf16(a[m], b[n], acc[m][n], 0, 0, 0);
    }
    __syncthreads();
  }

#pragma unroll
  for (int m = 0; m < 4; m++) {
#pragma unroll
    for (int rr = 0; rr < 4; rr++) {
      const int row = bmr + wr * 64 + m * 16 + g * 4 + rr;
#pragma unroll
      for (int n = 0; n < 4; n++) {
        const int col = bnr + wc * 64 + n * 16 + cr;
        float v = acc[m][n][rr];
        if (EPI == 0) {
          ((__hip_bfloat16*)outp)[(size_t)row * N + col] = __float2bfloat16(v);
        } else if (EPI == 2) {
          v = gelu_f(v + bias[col]);
          ((__hip_bfloat16*)outp)[(size_t)row * N + col] = __float2bfloat16(v);
        } else {  // EPI == 4: fp32 out, bf16 resid
          v += bias[col] +
               bf2f(((const short*)resid)[(size_t)row * N + col]);
          ((float*)outp)[(size_t)row * N + col] = v;
        }
      }
    }
  }
}

// ---------------------------------------------------------------------------
// Flash attention, causal (R17). Fixed-max softmax, MFMA-computed l,
// truncation P-pack, hoisted V fragments, pair-stacked equal work.
// ---------------------------------------------------------------------------
__global__ void __launch_bounds__(256) attn_kernel(
    const __hip_bfloat16* __restrict__ qkv, const __hip_bfloat16* __restrict__ vt,
    __hip_bfloat16* __restrict__ o) {
  __shared__ __hip_bfloat16 sK[2][64 * 64];   // [kv][hd], slot-swizzled
  __shared__ __hip_bfloat16 sV[2][64 * 64];   // [hd][kv], slot-swizzled
  __shared__ __hip_bfloat16 pl[4][16][64];    // per-wave P^T bounce, swizzled
  const int tid = threadIdx.x, lane = tid & 63, w = tid >> 6;
  const int orig = blockIdx.x;                 // 0..511
  const int f = (orig & 7) * 64 + (orig >> 3); // XCD-contiguous
  const int bh = f >> 3;
  const int p = f & 7;                         // pair id: (15-p, p)
  const int b = bh >> 4, h = bh & 15;
  const int cr = lane & 15, g = lane >> 4;
  const float NEG = -1e30f;
  const float SC2 = 0.18033688011112042f;      // 0.125 * log2(e)
  const int sw = cr & 7;
  const int sg0 = (g ^ sw) * 8;
  const int sg1 = ((g ^ sw) ^ 4) * 8;
  const int pkey = (cr & 7) << 1;

  bf16x8 vones;
#pragma unroll
  for (int j = 0; j < 8; j++) vones[j] = (short)0x3F80;  // bf16 1.0

  const __hip_bfloat16* kbase = qkv + (size_t)(b * 2048) * 3072 + 1024 + h * 64;
  const __hip_bfloat16* vbase = vt + (size_t)bh * 64 * 2048;
  const int l8 = lane >> 3, c8 = lane & 7;
  const int c8s = (c8 ^ l8) * 8;
#define STAGE_TILE(bi, ktile)                                                   \
  {                                                                             \
    _Pragma("unroll") for (int i = 0; i < 2; i++) {                             \
      const int rb = (i * 4 + w) * 8 + l8;                                      \
      gl_lds16(kbase + (size_t)((ktile) * 64 + rb) * 3072 + c8s,                \
               &sK[bi][(i * 4 + w) * 512]);                                     \
      gl_lds16(vbase + (size_t)rb * 2048 + (ktile) * 64 + c8s,                  \
               &sV[bi][(i * 4 + w) * 512]);                                     \
    }                                                                           \
  }

  for (int seg = 0; seg < 2; ++seg) {
    const int qt = seg == 0 ? (15 - p) : p;
    const int qr0 = qt * 128 + w * 32;

    bf16x8 aq[2][2];
#pragma unroll
    for (int m = 0; m < 2; m++) {
      const __hip_bfloat16* qp =
          qkv + (size_t)(b * 2048 + qr0 + m * 16 + cr) * 3072 + h * 64 + g * 8;
      bf16x8 q0 = *(const bf16x8*)qp;
      bf16x8 q1 = *(const bf16x8*)(qp + 32);
#pragma unroll
      for (int j = 0; j < 8; j++) {
        aq[m][0][j] = f2bf(bf2f(q0[j]) * SC2);
        aq[m][1][j] = f2bf(bf2f(q1[j]) * SC2);
      }
    }

    f32x4 oacc[2][4];
    f32x4 lacc[2];
#pragma unroll
    for (int m = 0; m < 2; m++) {
#pragma unroll
      for (int i = 0; i < 4; i++) oacc[m][i] = (f32x4){0.f, 0.f, 0.f, 0.f};
      lacc[m] = (f32x4){0.f, 0.f, 0.f, 0.f};
    }

    const int nkt = (qt + 1) * 2;
    __syncthreads();  // protect LDS buffers from previous segment's readers
    STAGE_TILE(0, 0);
    asm volatile("s_waitcnt vmcnt(0)" ::: "memory");
    __syncthreads();
    int cur = 0;

    for (int kt = 0; kt < nkt; ++kt) {
      if (kt + 1 < nkt) STAGE_TILE(cur ^ 1, kt + 1);

      if (kt * 64 <= qr0 + 31) {
        f32x4 st[4][2];  // [kf][mq]
        __builtin_amdgcn_s_setprio(1);
#pragma unroll
        for (int kf = 0; kf < 4; kf++) {
          const bf16x8 bk0 = *(const bf16x8*)&sK[cur][(kf * 16 + cr) * 64 + sg0];
          const bf16x8 bk1 = *(const bf16x8*)&sK[cur][(kf * 16 + cr) * 64 + sg1];
#pragma unroll
          for (int mq = 0; mq < 2; mq++) {
            f32x4 z = (f32x4){0.f, 0.f, 0.f, 0.f};
            z = __builtin_amdgcn_mfma_f32_16x16x32_bf16(bk0, aq[mq][0], z, 0, 0, 0);
            z = __builtin_amdgcn_mfma_f32_16x16x32_bf16(bk1, aq[mq][1], z, 0, 0, 0);
            st[kf][mq] = z;
          }
        }
        __builtin_amdgcn_s_setprio(0);
        if (kt * 64 + 63 > qr0) {
#pragma unroll
          for (int kf = 0; kf < 4; kf++)
#pragma unroll
            for (int mq = 0; mq < 2; mq++)
#pragma unroll
              for (int rr = 0; rr < 4; rr++) {
                const int kvcol = kt * 64 + kf * 16 + g * 4 + rr;
                const int qrow = qr0 + mq * 16 + cr;
                if (kvcol > qrow) st[kf][mq][rr] = NEG;
              }
        }
        bf16x8 bvv0[4], bvv1[4];
#pragma unroll
        for (int nf = 0; nf < 4; nf++) {
          bvv0[nf] = *(const bf16x8*)&sV[cur][(nf * 16 + cr) * 64 + sg0];
          bvv1[nf] = *(const bf16x8*)&sV[cur][(nf * 16 + cr) * 64 + sg1];
        }
#pragma unroll
        for (int mq = 0; mq < 2; mq++) {
#pragma unroll
          for (int kf = 0; kf < 4; kf++) {
            unsigned pb[4];
#pragma unroll
            for (int rr = 0; rr < 4; rr++) {
              const float pv = exp2f(st[kf][mq][rr]);
              pb[rr] = __builtin_bit_cast(unsigned, pv) & 0xFFFF0000u;
            }
            uint2 pk;
            pk.x = pb[1] | (pb[0] >> 16);
            pk.y = pb[3] | (pb[2] >> 16);
            const int slot4 = (kf * 4 + g) ^ pkey;
            *(uint2*)&pl[w][cr][slot4 * 4] = pk;
          }
          const bf16x8 pa0 = *(const bf16x8*)&pl[w][cr][((2 * g) ^ pkey) * 4];
          const bf16x8 pa1 = *(const bf16x8*)&pl[w][cr][((2 * g + 8) ^ pkey) * 4];
          __builtin_amdgcn_s_setprio(1);
#pragma unroll
          for (int nf = 0; nf < 4; nf++) {
            oacc[mq][nf] = __builtin_amdgcn_mfma_f32_16x16x32_bf16(pa0, bvv0[nf], oacc[mq][nf], 0, 0, 0);
            oacc[mq][nf] = __builtin_amdgcn_mfma_f32_16x16x32_bf16(pa1, bvv1[nf], oacc[mq][nf], 0, 0, 0);
          }
          lacc[mq] = __builtin_amdgcn_mfma_f32_16x16x32_bf16(pa0, vones, lacc[mq], 0, 0, 0);
          lacc[mq] = __builtin_amdgcn_mfma_f32_16x16x32_bf16(pa1, vones, lacc[mq], 0, 0, 0);
          __builtin_amdgcn_s_setprio(0);
        }
      }

      if (kt + 1 < nkt) {
        asm volatile("s_waitcnt vmcnt(0)" ::: "memory");
        __syncthreads();
        cur ^= 1;
      }
    }

#pragma unroll
    for (int m = 0; m < 2; m++) {
      float il[4];
#pragma unroll
      for (int rr = 0; rr < 4; rr++)
        il[rr] = 1.0f / lacc[m][rr];
#pragma unroll
      for (int nf = 0; nf < 4; nf++)
#pragma unroll
        for (int rr = 0; rr < 4; rr++) {
          const int row = qr0 + m * 16 + g * 4 + rr;
          o[(size_t)(b * 2048 + row) * 1024 + h * 64 + nf * 16 + cr] =
              __float2bfloat16(oacc[m][nf][rr] * il[rr]);
        }
    }
  }
#undef STAGE_TILE
}

// ---------------------------------------------------------------------------
// Launch
// ---------------------------------------------------------------------------
extern "C" void kernel_launch(void* const* d_in, const int* in_sizes, int n_in,
                              void* d_out, int out_size, void* d_ws, size_t ws_size,
                              hipStream_t stream) {
  const float* x   = (const float*)d_in[0];
  const float* Wq  = (const float*)d_in[1];
  const float* Wk  = (const float*)d_in[2];
  const float* Wv  = (const float*)d_in[3];
  const float* Wo  = (const float*)d_in[4];
  const float* bo  = (const float*)d_in[5];
  const float* W1  = (const float*)d_in[6];
  const float* b1  = (const float*)d_in[7];
  const float* W2  = (const float*)d_in[8];
  const float* b2  = (const float*)d_in[9];
  const float* g1  = (const float*)d_in[10];
  const float* be1 = (const float*)d_in[11];
  const float* g2  = (const float*)d_in[12];
  const float* be2 = (const float*)d_in[13];

  char* ws = (char*)d_ws;
  const size_t MB = 1024 * 1024;
  __hip_bfloat16* hA    = (__hip_bfloat16*)(ws + 0);          // 16MB (LN1 out)
  __hip_bfloat16* attnO = (__hip_bfloat16*)(ws + 0);          // 16MB (reuse)
  __hip_bfloat16* qkv   = (__hip_bfloat16*)(ws + 16 * MB);    // 48MB (V part unused)
  __hip_bfloat16* x2b   = (__hip_bfloat16*)(ws + 16 * MB);    // 16MB (reuse qkv; bf16 x2)
  __hip_bfloat16* h2    = (__hip_bfloat16*)(ws + 48 * MB);    // 16MB (reuse qkv tail)
  __hip_bfloat16* vtg   = (__hip_bfloat16*)(ws + 64 * MB);    // 16MB (dead after attn)
  __hip_bfloat16* act   = (__hip_bfloat16*)(ws + 64 * MB);    // 64MB (FFN1 out)
  __hip_bfloat16* WqkvT = (__hip_bfloat16*)(ws + 128 * MB);   // 6MB  [3072,1024]
  __hip_bfloat16* WoT   = (__hip_bfloat16*)(ws + 134 * MB);   // 2MB  [1024,1024]
  __hip_bfloat16* W1T   = (__hip_bfloat16*)(ws + 136 * MB);   // 8MB  [4096,1024]
  __hip_bfloat16* W2T   = (__hip_bfloat16*)(ws + 144 * MB);   // 8MB  [1024,4096]

  const dim3 tb(32, 8);
  tcvt_all<<<12288, tb, 0, stream>>>(Wq, Wk, Wv, Wo, W1, W2,
                                     WqkvT, WoT, W1T, W2T);

  ln_kernel<<<8192, 256, 0, stream>>>(x, g1, be1, hA);
  // QKV with fused V-transpose: V columns (bn>=8) go straight to vtg
  gemm8<128, 256, 5><<<dim3(64, 12), 512, 0, stream>>>(
      hA, WqkvT, qkv, nullptr, nullptr, 3072, 1024, vtg);
  // attn: 512 blocks (64 bh x 8 pairs), 4 waves, QBLK=128, equal work
  attn_kernel<<<512, 256, 0, stream>>>(qkv, vtg, attnO);
  // O-proj: bf16 x2 out (EPI3), resid = x (fp32)
  gemm8<128, 256, 3><<<dim3(64, 4), 512, 0, stream>>>(
      attnO, WoT, x2b, bo, x, 1024, 1024, nullptr);
  ln_bf16_kernel<<<8192, 256, 0, stream>>>(x2b, g2, be2, h2);
  // FFN1: gemm97 EPI2 (gelu), 64x32 = 2048 blocks (8 rounds)
  gemm97<2><<<dim3(64, 32), 256, 0, stream>>>(
      h2, W1T, act, b1, nullptr, 4096, 1024);
  // FFN2: fp32 out (EPI4), resid = x2b (bf16), K=4096
  gemm97<4><<<dim3(64, 8), 256, 0, stream>>>(
      act, W2T, (float*)d_out, b2, x2b, 1024, 4096);
  (void)in_sizes; (void)n_in; (void)out_size; (void)ws_size;
}

// Round 20
// 355.220 us; speedup vs baseline: 1.0642x; 1.0642x over previous
//
#include <hip/hip_runtime.h>
#include <hip/hip_bf16.h>
#include <math.h>

// ---------------------------------------------------------------------------
// TransformerBlock on MI355X (gfx950).
// QKV: gemm8<128,256> EPI5 -- V columns written TRANSPOSED directly to vt
//      (vtr kernel eliminated). O: gemm8 EPI3 (bf16 x2).
// FFN1: gemm8<256,256> EPI2 (measured-best 88us). FFN2: gemm97 EPI4.
// Attn: fixed-max softmax w/ MFMA-computed l. Supertile XCD mapping.
// ---------------------------------------------------------------------------

typedef __attribute__((ext_vector_type(8))) short bf16x8;
typedef __attribute__((ext_vector_type(4))) float f32x4;

#define AS1 __attribute__((address_space(1)))
#define AS3 __attribute__((address_space(3)))

__device__ __forceinline__ void gl_lds16(const void* g, void* l) {
  __builtin_amdgcn_global_load_lds((const AS1 void*)g, (AS3 void*)l, 16, 0, 0);
}

// Exact gelu-tanh via exp identity: tanh(|y|) = (1-e^{-2|y|})/(1+e^{-2|y|}).
__device__ __forceinline__ float gelu_f(float x) {
  const float c = 0.7978845608028654f;  // sqrt(2/pi)
  const float y = c * (x + 0.044715f * x * x * x);
  const float ay = fabsf(y);
  const float e = __expf(-2.0f * ay);
  float t = (1.0f - e) / (1.0f + e);
  t = copysignf(t, y);
  return 0.5f * x * (1.0f + t);
}

__device__ __forceinline__ float bf2f(short s) {
  unsigned u = ((unsigned)(unsigned short)s) << 16;
  return __builtin_bit_cast(float, u);
}
__device__ __forceinline__ short f2bf(float f) {
  __hip_bfloat16 h = __float2bfloat16(f);
  return __builtin_bit_cast(short, h);
}

// ---------------------------------------------------------------------------
// All weight transposes in ONE launch: W [K,N] fp32 -> WT [N,K] bf16
// ---------------------------------------------------------------------------
__global__ void __launch_bounds__(256) tcvt_all(
    const float* __restrict__ Wq, const float* __restrict__ Wk,
    const float* __restrict__ Wv, const float* __restrict__ Wo,
    const float* __restrict__ W1, const float* __restrict__ W2,
    __hip_bfloat16* __restrict__ WqkvT, __hip_bfloat16* __restrict__ WoT,
    __hip_bfloat16* __restrict__ W1T, __hip_bfloat16* __restrict__ W2T) {
  __shared__ float t[32][33];
  const int bid = blockIdx.x;
  const float* W;
  __hip_bfloat16* WT;
  int K, N, n0, k0;
  if (bid < 4096) {
    const int which = bid >> 10, r = bid & 1023;
    K = 1024; N = 1024;
    n0 = (r & 31) * 32; k0 = (r >> 5) * 32;
    W = which == 0 ? Wq : which == 1 ? Wk : which == 2 ? Wv : Wo;
    WT = which < 3 ? WqkvT + which * 1024 * 1024 : WoT;
  } else if (bid < 8192) {
    const int r = bid - 4096;
    K = 1024; N = 4096;
    n0 = (r & 127) * 32; k0 = (r >> 7) * 32;
    W = W1; WT = W1T;
  } else {
    const int r = bid - 8192;
    K = 4096; N = 1024;
    n0 = (r & 31) * 32; k0 = (r >> 5) * 32;
    W = W2; WT = W2T;
  }
  const int tx = threadIdx.x, ty0 = threadIdx.y;  // 32 x 8
#pragma unroll
  for (int i = 0; i < 4; i++) {
    int ty = ty0 + i * 8;
    t[ty][tx] = W[(size_t)(k0 + ty) * N + n0 + tx];
  }
  __syncthreads();
#pragma unroll
  for (int i = 0; i < 4; i++) {
    int ty = ty0 + i * 8;
    WT[(size_t)(n0 + ty) * K + k0 + tx] = __float2bfloat16(t[tx][ty]);
  }
}

// ---------------------------------------------------------------------------
// LayerNorm over D=1024 (fp32 in -> bf16 out)
// ---------------------------------------------------------------------------
__global__ void __launch_bounds__(256) ln_kernel(
    const float* __restrict__ x, const float* __restrict__ gma,
    const float* __restrict__ bta, __hip_bfloat16* __restrict__ out) {
  const int row = blockIdx.x;
  const int tid = threadIdx.x;
  const float4 v = ((const float4*)(x + (size_t)row * 1024))[tid];
  float s = v.x + v.y + v.z + v.w;
  float s2 = v.x * v.x + v.y * v.y + v.z * v.z + v.w * v.w;
#pragma unroll
  for (int m = 32; m; m >>= 1) {
    s += __shfl_xor(s, m);
    s2 += __shfl_xor(s2, m);
  }
  __shared__ float red[8];
  const int w = tid >> 6, lane = tid & 63;
  if (lane == 0) { red[w] = s; red[4 + w] = s2; }
  __syncthreads();
  s = red[0] + red[1] + red[2] + red[3];
  s2 = red[4] + red[5] + red[6] + red[7];
  const float mu = s * (1.0f / 1024.0f);
  const float var = s2 * (1.0f / 1024.0f) - mu * mu;
  const float rs = rsqrtf(var + 1e-5f);
  const float4 gv = ((const float4*)gma)[tid];
  const float4 bv = ((const float4*)bta)[tid];
  __hip_bfloat16* orow = out + (size_t)row * 1024 + tid * 4;
  orow[0] = __float2bfloat16((v.x - mu) * rs * gv.x + bv.x);
  orow[1] = __float2bfloat16((v.y - mu) * rs * gv.y + bv.y);
  orow[2] = __float2bfloat16((v.z - mu) * rs * gv.z + bv.z);
  orow[3] = __float2bfloat16((v.w - mu) * rs * gv.w + bv.w);
}

// ---------------------------------------------------------------------------
// LayerNorm over D=1024 (bf16 in -> bf16 out)
// ---------------------------------------------------------------------------
__global__ void __launch_bounds__(256) ln_bf16_kernel(
    const __hip_bfloat16* __restrict__ x, const float* __restrict__ gma,
    const float* __restrict__ bta, __hip_bfloat16* __restrict__ out) {
  const int row = blockIdx.x;
  const int tid = threadIdx.x;
  const short4 raw = ((const short4*)(x + (size_t)row * 1024))[tid];
  const float v0 = bf2f(raw.x), v1 = bf2f(raw.y), v2 = bf2f(raw.z),
              v3 = bf2f(raw.w);
  float s = v0 + v1 + v2 + v3;
  float s2 = v0 * v0 + v1 * v1 + v2 * v2 + v3 * v3;
#pragma unroll
  for (int m = 32; m; m >>= 1) {
    s += __shfl_xor(s, m);
    s2 += __shfl_xor(s2, m);
  }
  __shared__ float red[8];
  const int w = tid >> 6, lane = tid & 63;
  if (lane == 0) { red[w] = s; red[4 + w] = s2; }
  __syncthreads();
  s = red[0] + red[1] + red[2] + red[3];
  s2 = red[4] + red[5] + red[6] + red[7];
  const float mu = s * (1.0f / 1024.0f);
  const float var = s2 * (1.0f / 1024.0f) - mu * mu;
  const float rs = rsqrtf(var + 1e-5f);
  const float4 gv = ((const float4*)gma)[tid];
  const float4 bv = ((const float4*)bta)[tid];
  __hip_bfloat16* orow = out + (size_t)row * 1024 + tid * 4;
  orow[0] = __float2bfloat16((v0 - mu) * rs * gv.x + bv.x);
  orow[1] = __float2bfloat16((v1 - mu) * rs * gv.y + bv.y);
  orow[2] = __float2bfloat16((v2 - mu) * rs * gv.z + bv.z);
  orow[3] = __float2bfloat16((v3 - mu) * rs * gv.w + bv.w);
}

// ---------------------------------------------------------------------------
// GEMM, 8-phase, SINGLE barrier per phase. C = A*B^T, bf16 in, fp32 acc.
// EPI 0: bf16 | 2: bf16 gelu(.+bias) | 3: bf16 = .+bias+resid(fp32) |
// 5: QKV fused V-transpose (bnr>=2048 -> short4 transposed stores to vtp).
// ---------------------------------------------------------------------------
template <int BM, int BN, int EPI>
__global__ void __launch_bounds__(512, 2) gemm8(
    const __hip_bfloat16* __restrict__ Ap, const __hip_bfloat16* __restrict__ Bp,
    void* __restrict__ outp, const float* __restrict__ bias,
    const float* __restrict__ resid, int N, int K,
    __hip_bfloat16* __restrict__ vtp) {
  constexpr int PM = BM / 2;
  constexpr int MR = PM / 16;
  constexpr int NPH = MR / 2;
  constexpr int HA = BM / 128;
  constexpr int ABYTES = BM * 128;
  constexpr int BUFB = ABYTES + BN * 128;
  __shared__ __attribute__((aligned(128))) char smem[2 * BUFB];

  const int tid = threadIdx.x;
  const int lane = tid & 63, w = tid >> 6;
  const int wr = w >> 2, wc = w & 3;
  const int cr = lane & 15, g = lane >> 4;

  const int gx = gridDim.x;
  const int nwg = gx * gridDim.y;
  const int orig = blockIdx.y * gx + blockIdx.x;
  const int f = (orig & 7) * (nwg >> 3) + (orig >> 3);
  const int sid = f >> 4, wit = f & 15;
  const int stm = gx >> 2;
  const int bm = (sid % stm) * 4 + (wit & 3);
  const int bn = (sid / stm) * 4 + (wit >> 2);
  const int bmr = bm * BM, bnr = bn * BN;
  const int nkt = K >> 6;

  const int srow8 = lane >> 3;
  const int ssl = ((lane & 7) ^ srow8) * 8;
  unsigned aofs[2][2], bofs[2][2];
#pragma unroll
  for (int h = 0; h < 2; h++)
#pragma unroll
    for (int c = 0; c < 2; c++) {
      const int ha = (h < HA) ? h : 0;
      aofs[h][c] =
          (unsigned)(((bmr + ha * 128 + (w + c * 8) * 8 + srow8) * K + ssl) * 2);
      bofs[h][c] =
          (unsigned)(((bnr + h * 128 + (w + c * 8) * 8 + srow8) * K + ssl) * 2);
    }

  const int rk = cr & 7;
  const char* aP[2][2];
  const char* bP[2][2];
#pragma unroll
  for (int bf = 0; bf < 2; bf++)
#pragma unroll
    for (int ks = 0; ks < 2; ks++) {
      aP[bf][ks] =
          smem + bf * BUFB + (wr * PM + cr) * 128 + ((ks * 4 + g) ^ rk) * 16;
      bP[bf][ks] = smem + bf * BUFB + ABYTES + (wc * 64 + cr) * 128 +
                   ((ks * 4 + g) ^ rk) * 16;
    }

#define STG_A(BUF, tt, h)                                                     \
  do {                                                                        \
    const unsigned col = (unsigned)(tt) * 128u;                               \
    gl_lds16((const char*)Ap + aofs[h][0] + col,                              \
             smem + (BUF) * BUFB + (h) * 16384 + w * 1024);                   \
    gl_lds16((const char*)Ap + aofs[h][1] + col,                              \
             smem + (BUF) * BUFB + (h) * 16384 + (w + 8) * 1024);             \
  } while (0)
#define STG_B(BUF, tt, h)                                                     \
  do {                                                                        \
    const unsigned col = (unsigned)(tt) * 128u;                               \
    gl_lds16((const char*)Bp + bofs[h][0] + col,                              \
             smem + (BUF) * BUFB + ABYTES + (h) * 16384 + w * 1024);          \
    gl_lds16((const char*)Bp + bofs[h][1] + col,                              \
             smem + (BUF) * BUFB + ABYTES + (h) * 16384 + (w + 8) * 1024);    \
  } while (0)

  f32x4 acc[MR][4];
#pragma unroll
  for (int i = 0; i < MR; i++)
#pragma unroll
    for (int j = 0; j < 4; j++) acc[i][j] = (f32x4){0.f, 0.f, 0.f, 0.f};
  bf16x8 bv[4][2];

#pragma unroll
  for (int h = 0; h < HA; h++) STG_A(0, 0, h);
  STG_B(0, 0, 0); STG_B(0, 0, 1);
  STG_B(1, 1, 0); STG_B(1, 1, 1);

#define TILE_BODY(BUF, t)                                                     \
  {                                                                           \
    asm volatile("s_waitcnt vmcnt(4)" ::: "memory");                          \
    __builtin_amdgcn_s_barrier();                                             \
    const int tA = ((t) + 1 < nkt) ? (t) + 1 : (t) - 1;                       \
    const int tB = ((t) + 2 < nkt) ? (t) + 2 : (t);                           \
    _Pragma("unroll") for (int q = 0; q < NPH; q++) {                         \
      bf16x8 av[2][2];                                                        \
      _Pragma("unroll") for (int mm = 0; mm < 2; mm++)                        \
          _Pragma("unroll") for (int ks = 0; ks < 2; ks++) av[mm][ks] =       \
          *(const bf16x8*)(aP[BUF][ks] + (q * 2 + mm) * 2048);                \
      if (q == 0) {                                                           \
        _Pragma("unroll") for (int n = 0; n < 4; n++)                         \
            _Pragma("unroll") for (int ks = 0; ks < 2; ks++) bv[n][ks] =      \
            *(const bf16x8*)(bP[BUF][ks] + n * 2048);                         \
      }                                                                       \
      if constexpr (NPH == 4) {                                               \
        if (q == 0) { STG_A((BUF) ^ 1, tA, 0); }                              \
        else if (q == 1) { STG_A((BUF) ^ 1, tA, 1); }                         \
        else if (q == 2) { STG_B(BUF, tB, 0); }                               \
        else { STG_B(BUF, tB, 1); }                                           \
      } else {                                                                \
        if (q == 0) { STG_A((BUF) ^ 1, tA, 0); }                              \
        else { STG_B(BUF, tB, 0); STG_B(BUF, tB, 1); }                        \
      }                                                                       \
      __builtin_amdgcn_s_barrier();                                           \
      asm volatile("s_waitcnt lgkmcnt(0)" ::: "memory");                      \
      __builtin_amdgcn_s_setprio(1);                                          \
      _Pragma("unroll") for (int mm = 0; mm < 2; mm++)                        \
          _Pragma("unroll") for (int n = 0; n < 4; n++)                       \
              _Pragma("unroll") for (int ks = 0; ks < 2; ks++)                \
                  acc[q * 2 + mm][n] =                                        \
          __builtin_amdgcn_mfma_f32_16x16x32_bf16(av[mm][ks], bv[n][ks],      \
                                                  acc[q * 2 + mm][n], 0, 0, 0); \
      __builtin_amdgcn_s_setprio(0);                                          \
    }                                                                         \
  }

  for (int t = 0; t < nkt; t += 2) {
    TILE_BODY(0, t)
    TILE_BODY(1, t + 1)
  }
  asm volatile("s_waitcnt vmcnt(0)" ::: "memory");

  if (EPI == 5 && bnr >= 2048) {
    // V columns: write transposed to vtp[(b*1024 + hdg)*2048 + s].
    const int bq = bmr >> 11;
    const int sbase = (bmr & 2047) + wr * PM + g * 4;
#pragma unroll
    for (int m = 0; m < MR; m++) {
      const int s0 = sbase + m * 16;
#pragma unroll
      for (int n = 0; n < 4; n++) {
        const int hdg = bnr - 2048 + wc * 64 + n * 16 + cr;
        short4 pk;
        pk.x = f2bf(acc[m][n][0]);
        pk.y = f2bf(acc[m][n][1]);
        pk.z = f2bf(acc[m][n][2]);
        pk.w = f2bf(acc[m][n][3]);
        *(short4*)&vtp[((size_t)bq * 1024 + hdg) * 2048 + s0] = pk;
      }
    }
    return;
  }

#pragma unroll
  for (int m = 0; m < MR; m++) {
#pragma unroll
    for (int rr = 0; rr < 4; rr++) {
      const int row = bmr + wr * PM + m * 16 + g * 4 + rr;
#pragma unroll
      for (int n = 0; n < 4; n++) {
        const int col = bnr + wc * 64 + n * 16 + cr;
        float v = acc[m][n][rr];
        if (EPI == 0 || EPI == 5) {
          ((__hip_bfloat16*)outp)[(size_t)row * N + col] = __float2bfloat16(v);
        } else if (EPI == 2) {
          v = gelu_f(v + bias[col]);
          ((__hip_bfloat16*)outp)[(size_t)row * N + col] = __float2bfloat16(v);
        } else {  // EPI == 3: bf16 out, fp32 resid
          v += bias[col] + resid[(size_t)row * N + col];
          ((__hip_bfloat16*)outp)[(size_t)row * N + col] = __float2bfloat16(v);
        }
      }
    }
  }
#undef STG_A
#undef STG_B
#undef TILE_BODY
}

// ---------------------------------------------------------------------------
// GEMM, m97 structure: 128x128, 256 thr, single-buffer, supertile map.
// EPI 4: fp32 out = .+bias+resid(bf16)
// ---------------------------------------------------------------------------
template <int EPI>
__global__ void __launch_bounds__(256) gemm97(
    const __hip_bfloat16* __restrict__ Ap, const __hip_bfloat16* __restrict__ Bp,
    void* __restrict__ outp, const float* __restrict__ bias,
    const void* __restrict__ resid, int N, int K) {
  __shared__ __hip_bfloat16 sA[128 * 64];
  __shared__ __hip_bfloat16 sB[128 * 64];
  const int tid = threadIdx.x;
  const int lane = tid & 63, w = tid >> 6;
  const int wr = w >> 1, wc = w & 1;
  const int cr = lane & 15, g = lane >> 4;

  const int gx = gridDim.x;
  const int nwg = gx * gridDim.y;
  const int orig = blockIdx.y * gx + blockIdx.x;
  const int f = (orig & 7) * (nwg >> 3) + (orig >> 3);
  const int sid = f >> 4, wit = f & 15;
  const int stm = gx >> 2;
  const int bm = (sid % stm) * 4 + (wit & 3);
  const int bn = (sid / stm) * 4 + (wit >> 2);
  const int bmr = bm * 128, bnr = bn * 128;

  const int l8 = lane >> 3;
  const int ssl = ((lane & 7) ^ l8) * 8;
  const int rk = cr & 7;

  f32x4 acc[4][4];
#pragma unroll
  for (int i = 0; i < 4; i++)
#pragma unroll
    for (int j = 0; j < 4; j++) acc[i][j] = (f32x4){0.f, 0.f, 0.f, 0.f};

  for (int k0 = 0; k0 < K; k0 += 64) {
#pragma unroll
    for (int i = 0; i < 4; i++) {
      const int chunk = w * 4 + i;
      const int row = chunk * 8 + l8;
      gl_lds16(Ap + (size_t)(bmr + row) * K + k0 + ssl, sA + chunk * 512);
      gl_lds16(Bp + (size_t)(bnr + row) * K + k0 + ssl, sB + chunk * 512);
    }
    __syncthreads();
#pragma unroll
    for (int ks = 0; ks < 2; ks++) {
      bf16x8 a[4], b[4];
#pragma unroll
      for (int m = 0; m < 4; m++)
        a[m] = *(const bf16x8*)(sA + (wr * 64 + m * 16 + cr) * 64 +
                                ((ks * 4 + g) ^ rk) * 8);
#pragma unroll
      for (int n = 0; n < 4; n++)
        b[n] = *(const bf16x8*)(sB + (wc * 64 + n * 16 + cr) * 64 +
                                ((ks * 4 + g) ^ rk) * 8);
#pragma unroll
      for (int m = 0; m < 4; m++)
#pragma unroll
        for (int n = 0; n < 4; n++)
          acc[m][n] =
              __builtin_amdgcn_mfma_f32_16x16x32_bf16(a[m], b[n], acc[m][n], 0, 0, 0);
    }
    __syncthreads();
  }

#pragma unroll
  for (int m = 0; m < 4; m++) {
#pragma unroll
    for (int rr = 0; rr < 4; rr++) {
      const int row = bmr + wr * 64 + m * 16 + g * 4 + rr;
#pragma unroll
      for (int n = 0; n < 4; n++) {
        const int col = bnr + wc * 64 + n * 16 + cr;
        float v = acc[m][n][rr];
        if (EPI == 0) {
          ((__hip_bfloat16*)outp)[(size_t)row * N + col] = __float2bfloat16(v);
        } else {  // EPI == 4: fp32 out, bf16 resid
          v += bias[col] +
               bf2f(((const short*)resid)[(size_t)row * N + col]);
          ((float*)outp)[(size_t)row * N + col] = v;
        }
      }
    }
  }
}

// ---------------------------------------------------------------------------
// Flash attention, causal (R17). Fixed-max softmax, MFMA-computed l,
// truncation P-pack, hoisted V fragments, pair-stacked equal work.
// ---------------------------------------------------------------------------
__global__ void __launch_bounds__(256) attn_kernel(
    const __hip_bfloat16* __restrict__ qkv, const __hip_bfloat16* __restrict__ vt,
    __hip_bfloat16* __restrict__ o) {
  __shared__ __hip_bfloat16 sK[2][64 * 64];   // [kv][hd], slot-swizzled
  __shared__ __hip_bfloat16 sV[2][64 * 64];   // [hd][kv], slot-swizzled
  __shared__ __hip_bfloat16 pl[4][16][64];    // per-wave P^T bounce, swizzled
  const int tid = threadIdx.x, lane = tid & 63, w = tid >> 6;
  const int orig = blockIdx.x;                 // 0..511
  const int f = (orig & 7) * 64 + (orig >> 3); // XCD-contiguous
  const int bh = f >> 3;
  const int p = f & 7;                         // pair id: (15-p, p)
  const int b = bh >> 4, h = bh & 15;
  const int cr = lane & 15, g = lane >> 4;
  const float NEG = -1e30f;
  const float SC2 = 0.18033688011112042f;      // 0.125 * log2(e)
  const int sw = cr & 7;
  const int sg0 = (g ^ sw) * 8;
  const int sg1 = ((g ^ sw) ^ 4) * 8;
  const int pkey = (cr & 7) << 1;

  bf16x8 vones;
#pragma unroll
  for (int j = 0; j < 8; j++) vones[j] = (short)0x3F80;  // bf16 1.0

  const __hip_bfloat16* kbase = qkv + (size_t)(b * 2048) * 3072 + 1024 + h * 64;
  const __hip_bfloat16* vbase = vt + (size_t)bh * 64 * 2048;
  const int l8 = lane >> 3, c8 = lane & 7;
  const int c8s = (c8 ^ l8) * 8;
#define STAGE_TILE(bi, ktile)                                                   \
  {                                                                             \
    _Pragma("unroll") for (int i = 0; i < 2; i++) {                             \
      const int rb = (i * 4 + w) * 8 + l8;                                      \
      gl_lds16(kbase + (size_t)((ktile) * 64 + rb) * 3072 + c8s,                \
               &sK[bi][(i * 4 + w) * 512]);                                     \
      gl_lds16(vbase + (size_t)rb * 2048 + (ktile) * 64 + c8s,                  \
               &sV[bi][(i * 4 + w) * 512]);                                     \
    }                                                                           \
  }

  for (int seg = 0; seg < 2; ++seg) {
    const int qt = seg == 0 ? (15 - p) : p;
    const int qr0 = qt * 128 + w * 32;

    bf16x8 aq[2][2];
#pragma unroll
    for (int m = 0; m < 2; m++) {
      const __hip_bfloat16* qp =
          qkv + (size_t)(b * 2048 + qr0 + m * 16 + cr) * 3072 + h * 64 + g * 8;
      bf16x8 q0 = *(const bf16x8*)qp;
      bf16x8 q1 = *(const bf16x8*)(qp + 32);
#pragma unroll
      for (int j = 0; j < 8; j++) {
        aq[m][0][j] = f2bf(bf2f(q0[j]) * SC2);
        aq[m][1][j] = f2bf(bf2f(q1[j]) * SC2);
      }
    }

    f32x4 oacc[2][4];
    f32x4 lacc[2];
#pragma unroll
    for (int m = 0; m < 2; m++) {
#pragma unroll
      for (int i = 0; i < 4; i++) oacc[m][i] = (f32x4){0.f, 0.f, 0.f, 0.f};
      lacc[m] = (f32x4){0.f, 0.f, 0.f, 0.f};
    }

    const int nkt = (qt + 1) * 2;
    __syncthreads();  // protect LDS buffers from previous segment's readers
    STAGE_TILE(0, 0);
    asm volatile("s_waitcnt vmcnt(0)" ::: "memory");
    __syncthreads();
    int cur = 0;

    for (int kt = 0; kt < nkt; ++kt) {
      if (kt + 1 < nkt) STAGE_TILE(cur ^ 1, kt + 1);

      if (kt * 64 <= qr0 + 31) {
        f32x4 st[4][2];  // [kf][mq]
        __builtin_amdgcn_s_setprio(1);
#pragma unroll
        for (int kf = 0; kf < 4; kf++) {
          const bf16x8 bk0 = *(const bf16x8*)&sK[cur][(kf * 16 + cr) * 64 + sg0];
          const bf16x8 bk1 = *(const bf16x8*)&sK[cur][(kf * 16 + cr) * 64 + sg1];
#pragma unroll
          for (int mq = 0; mq < 2; mq++) {
            f32x4 z = (f32x4){0.f, 0.f, 0.f, 0.f};
            z = __builtin_amdgcn_mfma_f32_16x16x32_bf16(bk0, aq[mq][0], z, 0, 0, 0);
            z = __builtin_amdgcn_mfma_f32_16x16x32_bf16(bk1, aq[mq][1], z, 0, 0, 0);
            st[kf][mq] = z;
          }
        }
        __builtin_amdgcn_s_setprio(0);
        if (kt * 64 + 63 > qr0) {
#pragma unroll
          for (int kf = 0; kf < 4; kf++)
#pragma unroll
            for (int mq = 0; mq < 2; mq++)
#pragma unroll
              for (int rr = 0; rr < 4; rr++) {
                const int kvcol = kt * 64 + kf * 16 + g * 4 + rr;
                const int qrow = qr0 + mq * 16 + cr;
                if (kvcol > qrow) st[kf][mq][rr] = NEG;
              }
        }
        bf16x8 bvv0[4], bvv1[4];
#pragma unroll
        for (int nf = 0; nf < 4; nf++) {
          bvv0[nf] = *(const bf16x8*)&sV[cur][(nf * 16 + cr) * 64 + sg0];
          bvv1[nf] = *(const bf16x8*)&sV[cur][(nf * 16 + cr) * 64 + sg1];
        }
#pragma unroll
        for (int mq = 0; mq < 2; mq++) {
#pragma unroll
          for (int kf = 0; kf < 4; kf++) {
            unsigned pb[4];
#pragma unroll
            for (int rr = 0; rr < 4; rr++) {
              const float pv = exp2f(st[kf][mq][rr]);
              pb[rr] = __builtin_bit_cast(unsigned, pv) & 0xFFFF0000u;
            }
            uint2 pk;
            pk.x = pb[1] | (pb[0] >> 16);
            pk.y = pb[3] | (pb[2] >> 16);
            const int slot4 = (kf * 4 + g) ^ pkey;
            *(uint2*)&pl[w][cr][slot4 * 4] = pk;
          }
          const bf16x8 pa0 = *(const bf16x8*)&pl[w][cr][((2 * g) ^ pkey) * 4];
          const bf16x8 pa1 = *(const bf16x8*)&pl[w][cr][((2 * g + 8) ^ pkey) * 4];
          __builtin_amdgcn_s_setprio(1);
#pragma unroll
          for (int nf = 0; nf < 4; nf++) {
            oacc[mq][nf] = __builtin_amdgcn_mfma_f32_16x16x32_bf16(pa0, bvv0[nf], oacc[mq][nf], 0, 0, 0);
            oacc[mq][nf] = __builtin_amdgcn_mfma_f32_16x16x32_bf16(pa1, bvv1[nf], oacc[mq][nf], 0, 0, 0);
          }
          lacc[mq] = __builtin_amdgcn_mfma_f32_16x16x32_bf16(pa0, vones, lacc[mq], 0, 0, 0);
          lacc[mq] = __builtin_amdgcn_mfma_f32_16x16x32_bf16(pa1, vones, lacc[mq], 0, 0, 0);
          __builtin_amdgcn_s_setprio(0);
        }
      }

      if (kt + 1 < nkt) {
        asm volatile("s_waitcnt vmcnt(0)" ::: "memory");
        __syncthreads();
        cur ^= 1;
      }
    }

#pragma unroll
    for (int m = 0; m < 2; m++) {
      float il[4];
#pragma unroll
      for (int rr = 0; rr < 4; rr++)
        il[rr] = 1.0f / lacc[m][rr];
#pragma unroll
      for (int nf = 0; nf < 4; nf++)
#pragma unroll
        for (int rr = 0; rr < 4; rr++) {
          const int row = qr0 + m * 16 + g * 4 + rr;
          o[(size_t)(b * 2048 + row) * 1024 + h * 64 + nf * 16 + cr] =
              __float2bfloat16(oacc[m][nf][rr] * il[rr]);
        }
    }
  }
#undef STAGE_TILE
}

// ---------------------------------------------------------------------------
// Launch
// ---------------------------------------------------------------------------
extern "C" void kernel_launch(void* const* d_in, const int* in_sizes, int n_in,
                              void* d_out, int out_size, void* d_ws, size_t ws_size,
                              hipStream_t stream) {
  const float* x   = (const float*)d_in[0];
  const float* Wq  = (const float*)d_in[1];
  const float* Wk  = (const float*)d_in[2];
  const float* Wv  = (const float*)d_in[3];
  const float* Wo  = (const float*)d_in[4];
  const float* bo  = (const float*)d_in[5];
  const float* W1  = (const float*)d_in[6];
  const float* b1  = (const float*)d_in[7];
  const float* W2  = (const float*)d_in[8];
  const float* b2  = (const float*)d_in[9];
  const float* g1  = (const float*)d_in[10];
  const float* be1 = (const float*)d_in[11];
  const float* g2  = (const float*)d_in[12];
  const float* be2 = (const float*)d_in[13];

  char* ws = (char*)d_ws;
  const size_t MB = 1024 * 1024;
  __hip_bfloat16* hA    = (__hip_bfloat16*)(ws + 0);          // 16MB (LN1 out)
  __hip_bfloat16* attnO = (__hip_bfloat16*)(ws + 0);          // 16MB (reuse)
  __hip_bfloat16* qkv   = (__hip_bfloat16*)(ws + 16 * MB);    // 48MB (V part unused)
  __hip_bfloat16* x2b   = (__hip_bfloat16*)(ws + 16 * MB);    // 16MB (reuse qkv; bf16 x2)
  __hip_bfloat16* h2    = (__hip_bfloat16*)(ws + 48 * MB);    // 16MB (reuse qkv tail)
  __hip_bfloat16* vtg   = (__hip_bfloat16*)(ws + 64 * MB);    // 16MB (dead after attn)
  __hip_bfloat16* act   = (__hip_bfloat16*)(ws + 64 * MB);    // 64MB (FFN1 out)
  __hip_bfloat16* WqkvT = (__hip_bfloat16*)(ws + 128 * MB);   // 6MB  [3072,1024]
  __hip_bfloat16* WoT   = (__hip_bfloat16*)(ws + 134 * MB);   // 2MB  [1024,1024]
  __hip_bfloat16* W1T   = (__hip_bfloat16*)(ws + 136 * MB);   // 8MB  [4096,1024]
  __hip_bfloat16* W2T   = (__hip_bfloat16*)(ws + 144 * MB);   // 8MB  [1024,4096]

  const dim3 tb(32, 8);
  tcvt_all<<<12288, tb, 0, stream>>>(Wq, Wk, Wv, Wo, W1, W2,
                                     WqkvT, WoT, W1T, W2T);

  ln_kernel<<<8192, 256, 0, stream>>>(x, g1, be1, hA);
  // QKV with fused V-transpose: V columns (bnr>=2048) go straight to vtg
  gemm8<128, 256, 5><<<dim3(64, 12), 512, 0, stream>>>(
      hA, WqkvT, qkv, nullptr, nullptr, 3072, 1024, vtg);
  // attn: 512 blocks (64 bh x 8 pairs), 4 waves, QBLK=128, equal work
  attn_kernel<<<512, 256, 0, stream>>>(qkv, vtg, attnO);
  // O-proj: bf16 x2 out (EPI3), resid = x (fp32)
  gemm8<128, 256, 3><<<dim3(64, 4), 512, 0, stream>>>(
      attnO, WoT, x2b, bo, x, 1024, 1024, nullptr);
  ln_bf16_kernel<<<8192, 256, 0, stream>>>(x2b, g2, be2, h2);
  // FFN1: gemm8<256,256> EPI2 (measured-best: 88us, FETCH 49.5MB)
  gemm8<256, 256, 2><<<dim3(32, 16), 512, 0, stream>>>(
      h2, W1T, act, b1, nullptr, 4096, 1024, nullptr);
  // FFN2: fp32 out (EPI4), resid = x2b (bf16), K=4096
  gemm97<4><<<dim3(64, 8), 256, 0, stream>>>(
      act, W2T, (float*)d_out, b2, x2b, 1024, 4096);
  (void)in_sizes; (void)n_in; (void)out_size; (void)ws_size;
}

// Round 21
// 354.075 us; speedup vs baseline: 1.0676x; 1.0032x over previous
//
#include <hip/hip_runtime.h>
#include <hip/hip_bf16.h>
#include <math.h>

// ---------------------------------------------------------------------------
// TransformerBlock on MI355X (gfx950).
// QKV: gemm8<128,256> EPI5 (fused V-transpose). O: gemm8 EPI3 (bf16 x2).
// FFN1: gemm8<256,256> EPI2. FFN2: gemm97 EPI4. Supertile XCD mapping.
// Attn: fixed-max softmax w/ MFMA-computed l; NEW KVBLK=128 staging
// (half the vmcnt(0)+barrier drains; compute in 64-kv subtiles).
// ---------------------------------------------------------------------------

typedef __attribute__((ext_vector_type(8))) short bf16x8;
typedef __attribute__((ext_vector_type(4))) float f32x4;

#define AS1 __attribute__((address_space(1)))
#define AS3 __attribute__((address_space(3)))

__device__ __forceinline__ void gl_lds16(const void* g, void* l) {
  __builtin_amdgcn_global_load_lds((const AS1 void*)g, (AS3 void*)l, 16, 0, 0);
}

// Exact gelu-tanh via exp identity: tanh(|y|) = (1-e^{-2|y|})/(1+e^{-2|y|}).
__device__ __forceinline__ float gelu_f(float x) {
  const float c = 0.7978845608028654f;  // sqrt(2/pi)
  const float y = c * (x + 0.044715f * x * x * x);
  const float ay = fabsf(y);
  const float e = __expf(-2.0f * ay);
  float t = (1.0f - e) / (1.0f + e);
  t = copysignf(t, y);
  return 0.5f * x * (1.0f + t);
}

__device__ __forceinline__ float bf2f(short s) {
  unsigned u = ((unsigned)(unsigned short)s) << 16;
  return __builtin_bit_cast(float, u);
}
__device__ __forceinline__ short f2bf(float f) {
  __hip_bfloat16 h = __float2bfloat16(f);
  return __builtin_bit_cast(short, h);
}

// ---------------------------------------------------------------------------
// All weight transposes in ONE launch: W [K,N] fp32 -> WT [N,K] bf16
// ---------------------------------------------------------------------------
__global__ void __launch_bounds__(256) tcvt_all(
    const float* __restrict__ Wq, const float* __restrict__ Wk,
    const float* __restrict__ Wv, const float* __restrict__ Wo,
    const float* __restrict__ W1, const float* __restrict__ W2,
    __hip_bfloat16* __restrict__ WqkvT, __hip_bfloat16* __restrict__ WoT,
    __hip_bfloat16* __restrict__ W1T, __hip_bfloat16* __restrict__ W2T) {
  __shared__ float t[32][33];
  const int bid = blockIdx.x;
  const float* W;
  __hip_bfloat16* WT;
  int K, N, n0, k0;
  if (bid < 4096) {
    const int which = bid >> 10, r = bid & 1023;
    K = 1024; N = 1024;
    n0 = (r & 31) * 32; k0 = (r >> 5) * 32;
    W = which == 0 ? Wq : which == 1 ? Wk : which == 2 ? Wv : Wo;
    WT = which < 3 ? WqkvT + which * 1024 * 1024 : WoT;
  } else if (bid < 8192) {
    const int r = bid - 4096;
    K = 1024; N = 4096;
    n0 = (r & 127) * 32; k0 = (r >> 7) * 32;
    W = W1; WT = W1T;
  } else {
    const int r = bid - 8192;
    K = 4096; N = 1024;
    n0 = (r & 31) * 32; k0 = (r >> 5) * 32;
    W = W2; WT = W2T;
  }
  const int tx = threadIdx.x, ty0 = threadIdx.y;  // 32 x 8
#pragma unroll
  for (int i = 0; i < 4; i++) {
    int ty = ty0 + i * 8;
    t[ty][tx] = W[(size_t)(k0 + ty) * N + n0 + tx];
  }
  __syncthreads();
#pragma unroll
  for (int i = 0; i < 4; i++) {
    int ty = ty0 + i * 8;
    WT[(size_t)(n0 + ty) * K + k0 + tx] = __float2bfloat16(t[tx][ty]);
  }
}

// ---------------------------------------------------------------------------
// LayerNorm over D=1024 (fp32 in -> bf16 out)
// ---------------------------------------------------------------------------
__global__ void __launch_bounds__(256) ln_kernel(
    const float* __restrict__ x, const float* __restrict__ gma,
    const float* __restrict__ bta, __hip_bfloat16* __restrict__ out) {
  const int row = blockIdx.x;
  const int tid = threadIdx.x;
  const float4 v = ((const float4*)(x + (size_t)row * 1024))[tid];
  float s = v.x + v.y + v.z + v.w;
  float s2 = v.x * v.x + v.y * v.y + v.z * v.z + v.w * v.w;
#pragma unroll
  for (int m = 32; m; m >>= 1) {
    s += __shfl_xor(s, m);
    s2 += __shfl_xor(s2, m);
  }
  __shared__ float red[8];
  const int w = tid >> 6, lane = tid & 63;
  if (lane == 0) { red[w] = s; red[4 + w] = s2; }
  __syncthreads();
  s = red[0] + red[1] + red[2] + red[3];
  s2 = red[4] + red[5] + red[6] + red[7];
  const float mu = s * (1.0f / 1024.0f);
  const float var = s2 * (1.0f / 1024.0f) - mu * mu;
  const float rs = rsqrtf(var + 1e-5f);
  const float4 gv = ((const float4*)gma)[tid];
  const float4 bv = ((const float4*)bta)[tid];
  __hip_bfloat16* orow = out + (size_t)row * 1024 + tid * 4;
  orow[0] = __float2bfloat16((v.x - mu) * rs * gv.x + bv.x);
  orow[1] = __float2bfloat16((v.y - mu) * rs * gv.y + bv.y);
  orow[2] = __float2bfloat16((v.z - mu) * rs * gv.z + bv.z);
  orow[3] = __float2bfloat16((v.w - mu) * rs * gv.w + bv.w);
}

// ---------------------------------------------------------------------------
// LayerNorm over D=1024 (bf16 in -> bf16 out)
// ---------------------------------------------------------------------------
__global__ void __launch_bounds__(256) ln_bf16_kernel(
    const __hip_bfloat16* __restrict__ x, const float* __restrict__ gma,
    const float* __restrict__ bta, __hip_bfloat16* __restrict__ out) {
  const int row = blockIdx.x;
  const int tid = threadIdx.x;
  const short4 raw = ((const short4*)(x + (size_t)row * 1024))[tid];
  const float v0 = bf2f(raw.x), v1 = bf2f(raw.y), v2 = bf2f(raw.z),
              v3 = bf2f(raw.w);
  float s = v0 + v1 + v2 + v3;
  float s2 = v0 * v0 + v1 * v1 + v2 * v2 + v3 * v3;
#pragma unroll
  for (int m = 32; m; m >>= 1) {
    s += __shfl_xor(s, m);
    s2 += __shfl_xor(s2, m);
  }
  __shared__ float red[8];
  const int w = tid >> 6, lane = tid & 63;
  if (lane == 0) { red[w] = s; red[4 + w] = s2; }
  __syncthreads();
  s = red[0] + red[1] + red[2] + red[3];
  s2 = red[4] + red[5] + red[6] + red[7];
  const float mu = s * (1.0f / 1024.0f);
  const float var = s2 * (1.0f / 1024.0f) - mu * mu;
  const float rs = rsqrtf(var + 1e-5f);
  const float4 gv = ((const float4*)gma)[tid];
  const float4 bv = ((const float4*)bta)[tid];
  __hip_bfloat16* orow = out + (size_t)row * 1024 + tid * 4;
  orow[0] = __float2bfloat16((v0 - mu) * rs * gv.x + bv.x);
  orow[1] = __float2bfloat16((v1 - mu) * rs * gv.y + bv.y);
  orow[2] = __float2bfloat16((v2 - mu) * rs * gv.z + bv.z);
  orow[3] = __float2bfloat16((v3 - mu) * rs * gv.w + bv.w);
}

// ---------------------------------------------------------------------------
// GEMM, 8-phase, SINGLE barrier per phase. C = A*B^T, bf16 in, fp32 acc.
// EPI 0: bf16 | 2: bf16 gelu(.+bias) | 3: bf16 = .+bias+resid(fp32) |
// 5: QKV fused V-transpose (bnr>=2048 -> short4 transposed stores to vtp).
// ---------------------------------------------------------------------------
template <int BM, int BN, int EPI>
__global__ void __launch_bounds__(512, 2) gemm8(
    const __hip_bfloat16* __restrict__ Ap, const __hip_bfloat16* __restrict__ Bp,
    void* __restrict__ outp, const float* __restrict__ bias,
    const float* __restrict__ resid, int N, int K,
    __hip_bfloat16* __restrict__ vtp) {
  constexpr int PM = BM / 2;
  constexpr int MR = PM / 16;
  constexpr int NPH = MR / 2;
  constexpr int HA = BM / 128;
  constexpr int ABYTES = BM * 128;
  constexpr int BUFB = ABYTES + BN * 128;
  __shared__ __attribute__((aligned(128))) char smem[2 * BUFB];

  const int tid = threadIdx.x;
  const int lane = tid & 63, w = tid >> 6;
  const int wr = w >> 2, wc = w & 3;
  const int cr = lane & 15, g = lane >> 4;

  const int gx = gridDim.x;
  const int nwg = gx * gridDim.y;
  const int orig = blockIdx.y * gx + blockIdx.x;
  const int f = (orig & 7) * (nwg >> 3) + (orig >> 3);
  const int sid = f >> 4, wit = f & 15;
  const int stm = gx >> 2;
  const int bm = (sid % stm) * 4 + (wit & 3);
  const int bn = (sid / stm) * 4 + (wit >> 2);
  const int bmr = bm * BM, bnr = bn * BN;
  const int nkt = K >> 6;

  const int srow8 = lane >> 3;
  const int ssl = ((lane & 7) ^ srow8) * 8;
  unsigned aofs[2][2], bofs[2][2];
#pragma unroll
  for (int h = 0; h < 2; h++)
#pragma unroll
    for (int c = 0; c < 2; c++) {
      const int ha = (h < HA) ? h : 0;
      aofs[h][c] =
          (unsigned)(((bmr + ha * 128 + (w + c * 8) * 8 + srow8) * K + ssl) * 2);
      bofs[h][c] =
          (unsigned)(((bnr + h * 128 + (w + c * 8) * 8 + srow8) * K + ssl) * 2);
    }

  const int rk = cr & 7;
  const char* aP[2][2];
  const char* bP[2][2];
#pragma unroll
  for (int bf = 0; bf < 2; bf++)
#pragma unroll
    for (int ks = 0; ks < 2; ks++) {
      aP[bf][ks] =
          smem + bf * BUFB + (wr * PM + cr) * 128 + ((ks * 4 + g) ^ rk) * 16;
      bP[bf][ks] = smem + bf * BUFB + ABYTES + (wc * 64 + cr) * 128 +
                   ((ks * 4 + g) ^ rk) * 16;
    }

#define STG_A(BUF, tt, h)                                                     \
  do {                                                                        \
    const unsigned col = (unsigned)(tt) * 128u;                               \
    gl_lds16((const char*)Ap + aofs[h][0] + col,                              \
             smem + (BUF) * BUFB + (h) * 16384 + w * 1024);                   \
    gl_lds16((const char*)Ap + aofs[h][1] + col,                              \
             smem + (BUF) * BUFB + (h) * 16384 + (w + 8) * 1024);             \
  } while (0)
#define STG_B(BUF, tt, h)                                                     \
  do {                                                                        \
    const unsigned col = (unsigned)(tt) * 128u;                               \
    gl_lds16((const char*)Bp + bofs[h][0] + col,                              \
             smem + (BUF) * BUFB + ABYTES + (h) * 16384 + w * 1024);          \
    gl_lds16((const char*)Bp + bofs[h][1] + col,                              \
             smem + (BUF) * BUFB + ABYTES + (h) * 16384 + (w + 8) * 1024);    \
  } while (0)

  f32x4 acc[MR][4];
#pragma unroll
  for (int i = 0; i < MR; i++)
#pragma unroll
    for (int j = 0; j < 4; j++) acc[i][j] = (f32x4){0.f, 0.f, 0.f, 0.f};
  bf16x8 bv[4][2];

#pragma unroll
  for (int h = 0; h < HA; h++) STG_A(0, 0, h);
  STG_B(0, 0, 0); STG_B(0, 0, 1);
  STG_B(1, 1, 0); STG_B(1, 1, 1);

#define TILE_BODY(BUF, t)                                                     \
  {                                                                           \
    asm volatile("s_waitcnt vmcnt(4)" ::: "memory");                          \
    __builtin_amdgcn_s_barrier();                                             \
    const int tA = ((t) + 1 < nkt) ? (t) + 1 : (t) - 1;                       \
    const int tB = ((t) + 2 < nkt) ? (t) + 2 : (t);                           \
    _Pragma("unroll") for (int q = 0; q < NPH; q++) {                         \
      bf16x8 av[2][2];                                                        \
      _Pragma("unroll") for (int mm = 0; mm < 2; mm++)                        \
          _Pragma("unroll") for (int ks = 0; ks < 2; ks++) av[mm][ks] =       \
          *(const bf16x8*)(aP[BUF][ks] + (q * 2 + mm) * 2048);                \
      if (q == 0) {                                                           \
        _Pragma("unroll") for (int n = 0; n < 4; n++)                         \
            _Pragma("unroll") for (int ks = 0; ks < 2; ks++) bv[n][ks] =      \
            *(const bf16x8*)(bP[BUF][ks] + n * 2048);                         \
      }                                                                       \
      if constexpr (NPH == 4) {                                               \
        if (q == 0) { STG_A((BUF) ^ 1, tA, 0); }                              \
        else if (q == 1) { STG_A((BUF) ^ 1, tA, 1); }                         \
        else if (q == 2) { STG_B(BUF, tB, 0); }                               \
        else { STG_B(BUF, tB, 1); }                                           \
      } else {                                                                \
        if (q == 0) { STG_A((BUF) ^ 1, tA, 0); }                              \
        else { STG_B(BUF, tB, 0); STG_B(BUF, tB, 1); }                        \
      }                                                                       \
      __builtin_amdgcn_s_barrier();                                           \
      asm volatile("s_waitcnt lgkmcnt(0)" ::: "memory");                      \
      __builtin_amdgcn_s_setprio(1);                                          \
      _Pragma("unroll") for (int mm = 0; mm < 2; mm++)                        \
          _Pragma("unroll") for (int n = 0; n < 4; n++)                       \
              _Pragma("unroll") for (int ks = 0; ks < 2; ks++)                \
                  acc[q * 2 + mm][n] =                                        \
          __builtin_amdgcn_mfma_f32_16x16x32_bf16(av[mm][ks], bv[n][ks],      \
                                                  acc[q * 2 + mm][n], 0, 0, 0); \
      __builtin_amdgcn_s_setprio(0);                                          \
    }                                                                         \
  }

  for (int t = 0; t < nkt; t += 2) {
    TILE_BODY(0, t)
    TILE_BODY(1, t + 1)
  }
  asm volatile("s_waitcnt vmcnt(0)" ::: "memory");

  if (EPI == 5 && bnr >= 2048) {
    // V columns: write transposed to vtp[(b*1024 + hdg)*2048 + s].
    const int bq = bmr >> 11;
    const int sbase = (bmr & 2047) + wr * PM + g * 4;
#pragma unroll
    for (int m = 0; m < MR; m++) {
      const int s0 = sbase + m * 16;
#pragma unroll
      for (int n = 0; n < 4; n++) {
        const int hdg = bnr - 2048 + wc * 64 + n * 16 + cr;
        short4 pk;
        pk.x = f2bf(acc[m][n][0]);
        pk.y = f2bf(acc[m][n][1]);
        pk.z = f2bf(acc[m][n][2]);
        pk.w = f2bf(acc[m][n][3]);
        *(short4*)&vtp[((size_t)bq * 1024 + hdg) * 2048 + s0] = pk;
      }
    }
    return;
  }

#pragma unroll
  for (int m = 0; m < MR; m++) {
#pragma unroll
    for (int rr = 0; rr < 4; rr++) {
      const int row = bmr + wr * PM + m * 16 + g * 4 + rr;
#pragma unroll
      for (int n = 0; n < 4; n++) {
        const int col = bnr + wc * 64 + n * 16 + cr;
        float v = acc[m][n][rr];
        if (EPI == 0 || EPI == 5) {
          ((__hip_bfloat16*)outp)[(size_t)row * N + col] = __float2bfloat16(v);
        } else if (EPI == 2) {
          v = gelu_f(v + bias[col]);
          ((__hip_bfloat16*)outp)[(size_t)row * N + col] = __float2bfloat16(v);
        } else {  // EPI == 3: bf16 out, fp32 resid
          v += bias[col] + resid[(size_t)row * N + col];
          ((__hip_bfloat16*)outp)[(size_t)row * N + col] = __float2bfloat16(v);
        }
      }
    }
  }
#undef STG_A
#undef STG_B
#undef TILE_BODY
}

// ---------------------------------------------------------------------------
// GEMM, m97 structure: 128x128, 256 thr, single-buffer, supertile map.
// EPI 4: fp32 out = .+bias+resid(bf16)
// ---------------------------------------------------------------------------
template <int EPI>
__global__ void __launch_bounds__(256) gemm97(
    const __hip_bfloat16* __restrict__ Ap, const __hip_bfloat16* __restrict__ Bp,
    void* __restrict__ outp, const float* __restrict__ bias,
    const void* __restrict__ resid, int N, int K) {
  __shared__ __hip_bfloat16 sA[128 * 64];
  __shared__ __hip_bfloat16 sB[128 * 64];
  const int tid = threadIdx.x;
  const int lane = tid & 63, w = tid >> 6;
  const int wr = w >> 1, wc = w & 1;
  const int cr = lane & 15, g = lane >> 4;

  const int gx = gridDim.x;
  const int nwg = gx * gridDim.y;
  const int orig = blockIdx.y * gx + blockIdx.x;
  const int f = (orig & 7) * (nwg >> 3) + (orig >> 3);
  const int sid = f >> 4, wit = f & 15;
  const int stm = gx >> 2;
  const int bm = (sid % stm) * 4 + (wit & 3);
  const int bn = (sid / stm) * 4 + (wit >> 2);
  const int bmr = bm * 128, bnr = bn * 128;

  const int l8 = lane >> 3;
  const int ssl = ((lane & 7) ^ l8) * 8;
  const int rk = cr & 7;

  f32x4 acc[4][4];
#pragma unroll
  for (int i = 0; i < 4; i++)
#pragma unroll
    for (int j = 0; j < 4; j++) acc[i][j] = (f32x4){0.f, 0.f, 0.f, 0.f};

  for (int k0 = 0; k0 < K; k0 += 64) {
#pragma unroll
    for (int i = 0; i < 4; i++) {
      const int chunk = w * 4 + i;
      const int row = chunk * 8 + l8;
      gl_lds16(Ap + (size_t)(bmr + row) * K + k0 + ssl, sA + chunk * 512);
      gl_lds16(Bp + (size_t)(bnr + row) * K + k0 + ssl, sB + chunk * 512);
    }
    __syncthreads();
#pragma unroll
    for (int ks = 0; ks < 2; ks++) {
      bf16x8 a[4], b[4];
#pragma unroll
      for (int m = 0; m < 4; m++)
        a[m] = *(const bf16x8*)(sA + (wr * 64 + m * 16 + cr) * 64 +
                                ((ks * 4 + g) ^ rk) * 8);
#pragma unroll
      for (int n = 0; n < 4; n++)
        b[n] = *(const bf16x8*)(sB + (wc * 64 + n * 16 + cr) * 64 +
                                ((ks * 4 + g) ^ rk) * 8);
#pragma unroll
      for (int m = 0; m < 4; m++)
#pragma unroll
        for (int n = 0; n < 4; n++)
          acc[m][n] =
              __builtin_amdgcn_mfma_f32_16x16x32_bf16(a[m], b[n], acc[m][n], 0, 0, 0);
    }
    __syncthreads();
  }

#pragma unroll
  for (int m = 0; m < 4; m++) {
#pragma unroll
    for (int rr = 0; rr < 4; rr++) {
      const int row = bmr + wr * 64 + m * 16 + g * 4 + rr;
#pragma unroll
      for (int n = 0; n < 4; n++) {
        const int col = bnr + wc * 64 + n * 16 + cr;
        float v = acc[m][n][rr];
        if (EPI == 0) {
          ((__hip_bfloat16*)outp)[(size_t)row * N + col] = __float2bfloat16(v);
        } else {  // EPI == 4: fp32 out, bf16 resid
          v += bias[col] +
               bf2f(((const short*)resid)[(size_t)row * N + col]);
          ((float*)outp)[(size_t)row * N + col] = v;
        }
      }
    }
  }
}

// ---------------------------------------------------------------------------
// Flash attention, causal. 256 thr (4 waves), QBLK=128, KVBLK=128 staging
// (compute in 64-kv subtiles) -> half the vmcnt(0)+barrier drains.
// Fixed-max softmax, MFMA-computed l, truncation P-pack, hoisted V frags,
// pair-stacked equal work, XCD-chunked.
// sK [2][128x64] (128B rows, slot^=(row&7)); sV [2][64x128] (256B rows,
// slot low3 ^= (row&7), bit3 = kv-half) -- involutions on both sides.
// ---------------------------------------------------------------------------
__global__ void __launch_bounds__(256) attn_kernel(
    const __hip_bfloat16* __restrict__ qkv, const __hip_bfloat16* __restrict__ vt,
    __hip_bfloat16* __restrict__ o) {
  __shared__ __hip_bfloat16 sK[2][128 * 64];   // [kv][hd]
  __shared__ __hip_bfloat16 sV[2][64 * 128];   // [hd][kv]
  __shared__ __hip_bfloat16 pl[4][16][64];     // per-wave P^T bounce
  const int tid = threadIdx.x, lane = tid & 63, w = tid >> 6;
  const int orig = blockIdx.x;                 // 0..511
  const int f = (orig & 7) * 64 + (orig >> 3); // XCD-contiguous
  const int bh = f >> 3;
  const int p = f & 7;                         // pair id: (15-p, p)
  const int b = bh >> 4, h = bh & 15;
  const int cr = lane & 15, g = lane >> 4;
  const float NEG = -1e30f;
  const float SC2 = 0.18033688011112042f;      // 0.125 * log2(e)
  const int sw = cr & 7;
  const int sg0 = (g ^ sw) * 8;                // K read slots (64B row space)
  const int sg1 = ((g ^ sw) ^ 4) * 8;
  const int pkey = (cr & 7) << 1;

  bf16x8 vones;
#pragma unroll
  for (int j = 0; j < 8; j++) vones[j] = (short)0x3F80;  // bf16 1.0

  const __hip_bfloat16* kbase = qkv + (size_t)(b * 2048) * 3072 + 1024 + h * 64;
  const __hip_bfloat16* vbase = vt + (size_t)bh * 64 * 2048;
  const int l8 = lane >> 3, c8 = lane & 7;
  const int c8s = (c8 ^ l8) * 8;               // K source slot (8x16B rows)
  // V staging: chunk=(i*4+w) covers 4 rows of 256B; lane -> row chunk*4+(lane>>4),
  // slot lane&15. Source slot low3 ^= row&7 = ((w&1)<<2)|(lane>>4).
  const int vkey = ((w & 1) << 2) | (lane >> 4);
  const int vsrc = (((lane & 8) | ((lane & 7) ^ vkey))) * 8;
#define STAGE_TILE(bi, ktile)                                                   \
  {                                                                             \
    _Pragma("unroll") for (int i = 0; i < 4; i++) {                             \
      const int rbK = (i * 4 + w) * 8 + l8;                                     \
      gl_lds16(kbase + (size_t)((ktile) * 128 + rbK) * 3072 + c8s,              \
               &sK[bi][(i * 4 + w) * 512]);                                     \
    }                                                                           \
    _Pragma("unroll") for (int i = 0; i < 4; i++) {                             \
      const int rbV = (i * 4 + w) * 4 + (lane >> 4);                            \
      gl_lds16(vbase + (size_t)rbV * 2048 + (ktile) * 128 + vsrc,               \
               &sV[bi][(i * 4 + w) * 512]);                                     \
    }                                                                           \
  }

  for (int seg = 0; seg < 2; ++seg) {
    const int qt = seg == 0 ? (15 - p) : p;
    const int qr0 = qt * 128 + w * 32;

    bf16x8 aq[2][2];
#pragma unroll
    for (int m = 0; m < 2; m++) {
      const __hip_bfloat16* qp =
          qkv + (size_t)(b * 2048 + qr0 + m * 16 + cr) * 3072 + h * 64 + g * 8;
      bf16x8 q0 = *(const bf16x8*)qp;
      bf16x8 q1 = *(const bf16x8*)(qp + 32);
#pragma unroll
      for (int j = 0; j < 8; j++) {
        aq[m][0][j] = f2bf(bf2f(q0[j]) * SC2);
        aq[m][1][j] = f2bf(bf2f(q1[j]) * SC2);
      }
    }

    f32x4 oacc[2][4];
    f32x4 lacc[2];
#pragma unroll
    for (int m = 0; m < 2; m++) {
#pragma unroll
      for (int i = 0; i < 4; i++) oacc[m][i] = (f32x4){0.f, 0.f, 0.f, 0.f};
      lacc[m] = (f32x4){0.f, 0.f, 0.f, 0.f};
    }

    const int nkt = qt + 1;  // 128-row kv tiles
    __syncthreads();  // protect LDS buffers from previous segment's readers
    STAGE_TILE(0, 0);
    asm volatile("s_waitcnt vmcnt(0)" ::: "memory");
    __syncthreads();
    int cur = 0;

    for (int kt = 0; kt < nkt; ++kt) {
      if (kt + 1 < nkt) STAGE_TILE(cur ^ 1, kt + 1);

#pragma unroll
      for (int sub = 0; sub < 2; ++sub) {
        const int kvb = kt * 128 + sub * 64;
        if (kvb > qr0 + 31) continue;

        f32x4 st[4][2];  // [kf][mq]
        __builtin_amdgcn_s_setprio(1);
#pragma unroll
        for (int kf = 0; kf < 4; kf++) {
          const int krow = (sub * 64 + kf * 16 + cr) * 64;
          const bf16x8 bk0 = *(const bf16x8*)&sK[cur][krow + sg0];
          const bf16x8 bk1 = *(const bf16x8*)&sK[cur][krow + sg1];
#pragma unroll
          for (int mq = 0; mq < 2; mq++) {
            f32x4 z = (f32x4){0.f, 0.f, 0.f, 0.f};
            z = __builtin_amdgcn_mfma_f32_16x16x32_bf16(bk0, aq[mq][0], z, 0, 0, 0);
            z = __builtin_amdgcn_mfma_f32_16x16x32_bf16(bk1, aq[mq][1], z, 0, 0, 0);
            st[kf][mq] = z;
          }
        }
        __builtin_amdgcn_s_setprio(0);
        if (kvb + 63 > qr0) {
#pragma unroll
          for (int kf = 0; kf < 4; kf++)
#pragma unroll
            for (int mq = 0; mq < 2; mq++)
#pragma unroll
              for (int rr = 0; rr < 4; rr++) {
                const int kvcol = kvb + kf * 16 + g * 4 + rr;
                const int qrow = qr0 + mq * 16 + cr;
                if (kvcol > qrow) st[kf][mq][rr] = NEG;
              }
        }
        bf16x8 bvv0[4], bvv1[4];
#pragma unroll
        for (int nf = 0; nf < 4; nf++) {
          const int vrow = (nf * 16 + cr) * 128 + sub * 64;
          bvv0[nf] = *(const bf16x8*)&sV[cur][vrow + sg0];
          bvv1[nf] = *(const bf16x8*)&sV[cur][vrow + sg1];
        }
#pragma unroll
        for (int mq = 0; mq < 2; mq++) {
#pragma unroll
          for (int kf = 0; kf < 4; kf++) {
            unsigned pb[4];
#pragma unroll
            for (int rr = 0; rr < 4; rr++) {
              const float pv = exp2f(st[kf][mq][rr]);
              pb[rr] = __builtin_bit_cast(unsigned, pv) & 0xFFFF0000u;
            }
            uint2 pk;
            pk.x = pb[1] | (pb[0] >> 16);
            pk.y = pb[3] | (pb[2] >> 16);
            const int slot4 = (kf * 4 + g) ^ pkey;
            *(uint2*)&pl[w][cr][slot4 * 4] = pk;
          }
          const bf16x8 pa0 = *(const bf16x8*)&pl[w][cr][((2 * g) ^ pkey) * 4];
          const bf16x8 pa1 = *(const bf16x8*)&pl[w][cr][((2 * g + 8) ^ pkey) * 4];
          __builtin_amdgcn_s_setprio(1);
#pragma unroll
          for (int nf = 0; nf < 4; nf++) {
            oacc[mq][nf] = __builtin_amdgcn_mfma_f32_16x16x32_bf16(pa0, bvv0[nf], oacc[mq][nf], 0, 0, 0);
            oacc[mq][nf] = __builtin_amdgcn_mfma_f32_16x16x32_bf16(pa1, bvv1[nf], oacc[mq][nf], 0, 0, 0);
          }
          lacc[mq] = __builtin_amdgcn_mfma_f32_16x16x32_bf16(pa0, vones, lacc[mq], 0, 0, 0);
          lacc[mq] = __builtin_amdgcn_mfma_f32_16x16x32_bf16(pa1, vones, lacc[mq], 0, 0, 0);
          __builtin_amdgcn_s_setprio(0);
        }
      }

      if (kt + 1 < nkt) {
        asm volatile("s_waitcnt vmcnt(0)" ::: "memory");
        __syncthreads();
        cur ^= 1;
      }
    }

#pragma unroll
    for (int m = 0; m < 2; m++) {
      float il[4];
#pragma unroll
      for (int rr = 0; rr < 4; rr++)
        il[rr] = 1.0f / lacc[m][rr];
#pragma unroll
      for (int nf = 0; nf < 4; nf++)
#pragma unroll
        for (int rr = 0; rr < 4; rr++) {
          const int row = qr0 + m * 16 + g * 4 + rr;
          o[(size_t)(b * 2048 + row) * 1024 + h * 64 + nf * 16 + cr] =
              __float2bfloat16(oacc[m][nf][rr] * il[rr]);
        }
    }
  }
#undef STAGE_TILE
}

// ---------------------------------------------------------------------------
// Launch
// ---------------------------------------------------------------------------
extern "C" void kernel_launch(void* const* d_in, const int* in_sizes, int n_in,
                              void* d_out, int out_size, void* d_ws, size_t ws_size,
                              hipStream_t stream) {
  const float* x   = (const float*)d_in[0];
  const float* Wq  = (const float*)d_in[1];
  const float* Wk  = (const float*)d_in[2];
  const float* Wv  = (const float*)d_in[3];
  const float* Wo  = (const float*)d_in[4];
  const float* bo  = (const float*)d_in[5];
  const float* W1  = (const float*)d_in[6];
  const float* b1  = (const float*)d_in[7];
  const float* W2  = (const float*)d_in[8];
  const float* b2  = (const float*)d_in[9];
  const float* g1  = (const float*)d_in[10];
  const float* be1 = (const float*)d_in[11];
  const float* g2  = (const float*)d_in[12];
  const float* be2 = (const float*)d_in[13];

  char* ws = (char*)d_ws;
  const size_t MB = 1024 * 1024;
  __hip_bfloat16* hA    = (__hip_bfloat16*)(ws + 0);          // 16MB (LN1 out)
  __hip_bfloat16* attnO = (__hip_bfloat16*)(ws + 0);          // 16MB (reuse)
  __hip_bfloat16* qkv   = (__hip_bfloat16*)(ws + 16 * MB);    // 48MB (V part unused)
  __hip_bfloat16* x2b   = (__hip_bfloat16*)(ws + 16 * MB);    // 16MB (reuse qkv; bf16 x2)
  __hip_bfloat16* h2    = (__hip_bfloat16*)(ws + 48 * MB);    // 16MB (reuse qkv tail)
  __hip_bfloat16* vtg   = (__hip_bfloat16*)(ws + 64 * MB);    // 16MB (dead after attn)
  __hip_bfloat16* act   = (__hip_bfloat16*)(ws + 64 * MB);    // 64MB (FFN1 out)
  __hip_bfloat16* WqkvT = (__hip_bfloat16*)(ws + 128 * MB);   // 6MB  [3072,1024]
  __hip_bfloat16* WoT   = (__hip_bfloat16*)(ws + 134 * MB);   // 2MB  [1024,1024]
  __hip_bfloat16* W1T   = (__hip_bfloat16*)(ws + 136 * MB);   // 8MB  [4096,1024]
  __hip_bfloat16* W2T   = (__hip_bfloat16*)(ws + 144 * MB);   // 8MB  [1024,4096]

  const dim3 tb(32, 8);
  tcvt_all<<<12288, tb, 0, stream>>>(Wq, Wk, Wv, Wo, W1, W2,
                                     WqkvT, WoT, W1T, W2T);

  ln_kernel<<<8192, 256, 0, stream>>>(x, g1, be1, hA);
  // QKV with fused V-transpose: V columns (bnr>=2048) go straight to vtg
  gemm8<128, 256, 5><<<dim3(64, 12), 512, 0, stream>>>(
      hA, WqkvT, qkv, nullptr, nullptr, 3072, 1024, vtg);
  // attn: 512 blocks (64 bh x 8 pairs), 4 waves, QBLK=128, KVBLK=128
  attn_kernel<<<512, 256, 0, stream>>>(qkv, vtg, attnO);
  // O-proj: bf16 x2 out (EPI3), resid = x (fp32)
  gemm8<128, 256, 3><<<dim3(64, 4), 512, 0, stream>>>(
      attnO, WoT, x2b, bo, x, 1024, 1024, nullptr);
  ln_bf16_kernel<<<8192, 256, 0, stream>>>(x2b, g2, be2, h2);
  // FFN1: gemm8<256,256> EPI2 (measured-best)
  gemm8<256, 256, 2><<<dim3(32, 16), 512, 0, stream>>>(
      h2, W1T, act, b1, nullptr, 4096, 1024, nullptr);
  // FFN2: fp32 out (EPI4), resid = x2b (bf16), K=4096
  gemm97<4><<<dim3(64, 8), 256, 0, stream>>>(
      act, W2T, (float*)d_out, b2, x2b, 1024, 4096);
  (void)in_sizes; (void)n_in; (void)out_size; (void)ws_size;
}